// Round 2
// baseline (16001.421 us; speedup 1.0000x reference)
//
#include <hip/hip_runtime.h>
#include <math.h>

// Problem constants
#define BB   64
#define NN   1024
#define DIN  16
#define DD   256
#define HH   4
#define LL   3
#define DHH  64
#define DFF2 1024
#define KSEL 64

// ---------------------------------------------------------------------------
// Embedding: h[row, :] = x[row, :16] @ emb_W + emb_b.  4 rows per block.
// ---------------------------------------------------------------------------
__global__ __launch_bounds__(256) void embed_kernel(
    const float* __restrict__ x, const float* __restrict__ W,
    const float* __restrict__ bias, float* __restrict__ h)
{
  __shared__ float xs[4][DIN];
  const int t = threadIdx.x, w = t >> 6, lane = t & 63;
  const size_t row = (size_t)blockIdx.x * 4 + w;
  if (lane < DIN) xs[w][lane] = x[row * DIN + lane];
  __syncthreads();
#pragma unroll
  for (int j = 0; j < 4; ++j) {
    const int col = lane + j * 64;
    float acc = bias[col];
#pragma unroll
    for (int kk = 0; kk < DIN; ++kk) acc = fmaf(xs[w][kk], W[kk * DD + col], acc);
    h[row * DD + col] = acc;
  }
}

// ---------------------------------------------------------------------------
// Generic fp32 GEMM: C[M,N] = A[M,K] @ B[K,N] (+bias)(+res)(relu)(accum)
// 64x64 tile, BK=16, 256 threads, 4x4 per thread.
// LDS rows padded to 68 floats: keeps float4 16B alignment (272B stride) and
// <=2-way bank aliasing (free on CDNA4 per m136).
// Grid: (N/64, M/64). All shapes here are multiples of the tile.
// ---------------------------------------------------------------------------
__global__ __launch_bounds__(256) void gemm_kernel(
    const float* __restrict__ A, int lda,
    const float* __restrict__ Bm, int ldb,
    float* C, int ldc,
    const float* __restrict__ bias,
    const float* res, int ldres,
    int Kk, int relu, int accum)
{
  __shared__ __align__(16) float As[16][68];
  __shared__ __align__(16) float Bs[16][68];
  const int t = threadIdx.x;
  const int tx = t & 15, ty = t >> 4;
  const size_t row0 = (size_t)blockIdx.y * 64;
  const size_t col0 = (size_t)blockIdx.x * 64;
  const int arow = t >> 2, akq = (t & 3) * 4;   // A loader: 64 rows x 16 k
  const int brow = t >> 4, bcol = (t & 15) * 4; // B loader: 16 k x 64 cols
  float acc[4][4] = {};
  const float* Aptr = A + (row0 + arow) * lda + akq;
  const float* Bptr = Bm + (size_t)brow * ldb + col0 + bcol;
  for (int k0 = 0; k0 < Kk; k0 += 16) {
    const float4 av = *(const float4*)(Aptr + k0);
    const float4 bv = *(const float4*)(Bptr + (size_t)k0 * ldb);
    As[akq + 0][arow] = av.x; As[akq + 1][arow] = av.y;
    As[akq + 2][arow] = av.z; As[akq + 3][arow] = av.w;
    *(float4*)&Bs[brow][bcol] = bv;
    __syncthreads();
#pragma unroll
    for (int kk = 0; kk < 16; ++kk) {
      const float4 a4 = *(const float4*)&As[kk][ty * 4];
      const float4 b4 = *(const float4*)&Bs[kk][tx * 4];
      const float aa[4] = {a4.x, a4.y, a4.z, a4.w};
      const float bb2[4] = {b4.x, b4.y, b4.z, b4.w};
#pragma unroll
      for (int i = 0; i < 4; ++i)
#pragma unroll
        for (int j = 0; j < 4; ++j)
          acc[i][j] = fmaf(aa[i], bb2[j], acc[i][j]);
    }
    __syncthreads();
  }
#pragma unroll
  for (int i = 0; i < 4; ++i) {
    const size_t r = row0 + ty * 4 + i;
#pragma unroll
    for (int j = 0; j < 4; ++j) {
      const size_t c = col0 + tx * 4 + j;
      float v = acc[i][j];
      if (bias) v += bias[c];
      if (res)  v += res[r * (size_t)ldres + c];  // in-place safe: element read only by its own writer thread
      if (relu) v = fmaxf(v, 0.f);
      float* cp = C + r * (size_t)ldc + c;
      if (accum) v += *cp;
      *cp = v;
    }
  }
}

// ---------------------------------------------------------------------------
// Fused attention for one (b, head, 8-row q-tile) within a batch CHUNK.
// q/k/v are chunk-local [bchunk][1024][256]; o likewise (separate buffer).
// scores [8][1024] live in LDS; wave-parallel softmax; PV with transposed
// V tile so the c-dim is float4-contiguous.
// ---------------------------------------------------------------------------
__global__ __launch_bounds__(256) void attn_kernel(
    const float* __restrict__ qb, const float* __restrict__ kb,
    const float* __restrict__ vb, float* __restrict__ ob)
{
  __shared__ __align__(16) float S[8][NN + 4];
  __shared__ __align__(16) float Qs[8][DHH + 4];
  __shared__ __align__(16) float KV[64][DHH + 4];   // K tile, then reused as V^T tile
  __shared__ float rowsum[8];
  const int t = threadIdx.x;
  const int qt = blockIdx.x, hh = blockIdx.y, b = blockIdx.z;
  const size_t base = ((size_t)b * NN) * DD + (size_t)hh * DHH;

  { // load Q tile 8x64
    const int r = t >> 5, d0 = (t & 31) * 2;
    const float* qp = qb + base + (size_t)(qt * 8 + r) * DD + d0;
    Qs[r][d0] = qp[0]; Qs[r][d0 + 1] = qp[1];
  }
  __syncthreads();

  // ---- scores = (Q K^T) * 1/sqrt(64) ----
  const int qr = t & 7, kc = (t >> 3) * 2;
  for (int n0 = 0; n0 < NN; n0 += 64) {
    { // K tile [64 rows][64 d]
      const int r = t >> 2, c0 = (t & 3) * 16;
      const float* kp = kb + base + (size_t)(n0 + r) * DD + c0;
#pragma unroll
      for (int u = 0; u < 16; u += 4)
        *(float4*)&KV[r][c0 + u] = *(const float4*)(kp + u);
    }
    __syncthreads();
    float s0 = 0.f, s1 = 0.f;
#pragma unroll
    for (int d0 = 0; d0 < DHH; d0 += 4) {
      const float4 q4  = *(const float4*)&Qs[qr][d0];
      const float4 ka  = *(const float4*)&KV[kc][d0];
      const float4 kb4 = *(const float4*)&KV[kc + 1][d0];
      s0 += q4.x * ka.x  + q4.y * ka.y  + q4.z * ka.z  + q4.w * ka.w;
      s1 += q4.x * kb4.x + q4.y * kb4.y + q4.z * kb4.z + q4.w * kb4.w;
    }
    S[qr][n0 + kc]     = s0 * 0.125f;
    S[qr][n0 + kc + 1] = s1 * 0.125f;
    __syncthreads();
  }

  // ---- softmax per row (each wave owns rows w, w+4; shfl-only reduce) ----
  {
    const int w = t >> 6, lane = t & 63;
    for (int r = w; r < 8; r += 4) {
      float vals[16]; float m = -1e30f;
#pragma unroll
      for (int j = 0; j < 16; ++j) { vals[j] = S[r][lane + j * 64]; m = fmaxf(m, vals[j]); }
#pragma unroll
      for (int off = 32; off; off >>= 1) m = fmaxf(m, __shfl_xor(m, off));
      float ls = 0.f;
#pragma unroll
      for (int j = 0; j < 16; ++j) {
        const float e = expf(vals[j] - m);
        S[r][lane + j * 64] = e;
        ls += e;
      }
#pragma unroll
      for (int off = 32; off; off >>= 1) ls += __shfl_xor(ls, off);
      if (lane == 0) rowsum[r] = ls;
    }
  }
  __syncthreads();

  // ---- PV: o[qr][d] = sum_c P[qr][c] V[c][d] / rowsum ----
  const int qr3 = t >> 5, dd = t & 31;  // dd fast-varying -> coalesced output
  float acc0 = 0.f, acc1 = 0.f;
  for (int n0 = 0; n0 < NN; n0 += 64) {
    { // V tile stored transposed: KV[d][c]
      const int c = t >> 2, d0 = (t & 3) * 16;
      const float* vp = vb + base + (size_t)(n0 + c) * DD + d0;
#pragma unroll
      for (int u = 0; u < 16; u += 4) {
        const float4 v4 = *(const float4*)(vp + u);
        KV[d0 + u + 0][c] = v4.x; KV[d0 + u + 1][c] = v4.y;
        KV[d0 + u + 2][c] = v4.z; KV[d0 + u + 3][c] = v4.w;
      }
    }
    __syncthreads();
#pragma unroll
    for (int c4 = 0; c4 < 64; c4 += 4) {
      const float4 p4  = *(const float4*)&S[qr3][n0 + c4];
      const float4 va  = *(const float4*)&KV[dd][c4];
      const float4 vb4 = *(const float4*)&KV[dd + 32][c4];
      acc0 += p4.x * va.x  + p4.y * va.y  + p4.z * va.z  + p4.w * va.w;
      acc1 += p4.x * vb4.x + p4.y * vb4.y + p4.z * vb4.z + p4.w * vb4.w;
    }
    __syncthreads();
  }
  const float inv = 1.f / rowsum[qr3];
  float* op = ob + base + (size_t)(qt * 8 + qr3) * DD + dd;
  op[0]  = acc0 * inv;
  op[32] = acc1 * inv;
}

// ---------------------------------------------------------------------------
// LayerNorm over D=256, 4 rows/block (one wave per row, shfl reduce).
// ---------------------------------------------------------------------------
__global__ __launch_bounds__(256) void ln_kernel(
    const float* in, float* out,
    const float* __restrict__ g, const float* __restrict__ bb)
{
  const int t = threadIdx.x, w = t >> 6, lane = t & 63;
  const size_t row = (size_t)blockIdx.x * 4 + w;
  const float4 val = *(const float4*)(in + row * DD + lane * 4);
  float s = val.x + val.y + val.z + val.w;
#pragma unroll
  for (int off = 32; off; off >>= 1) s += __shfl_xor(s, off);
  const float mean = s * (1.f / 256.f);
  const float dx = val.x - mean, dy = val.y - mean, dz = val.z - mean, dw = val.w - mean;
  float ss = dx * dx + dy * dy + dz * dz + dw * dw;
#pragma unroll
  for (int off = 32; off; off >>= 1) ss += __shfl_xor(ss, off);
  const float inv = rsqrtf(ss * (1.f / 256.f) + 1e-5f);
  const float4 g4 = *(const float4*)(g + lane * 4);
  const float4 b4 = *(const float4*)(bb + lane * 4);
  float4 o4;
  o4.x = dx * inv * g4.x + b4.x;
  o4.y = dy * inv * g4.y + b4.y;
  o4.z = dz * inv * g4.z + b4.z;
  o4.w = dw * inv * g4.w + b4.w;
  *(float4*)(out + row * DD + lane * 4) = o4;
}

// ---------------------------------------------------------------------------
// h_mean[b, :] = mean over N of h[b, :, :]
// ---------------------------------------------------------------------------
__global__ __launch_bounds__(256) void rowmean_kernel(
    const float* __restrict__ h, float* __restrict__ hm)
{
  const int t = threadIdx.x, b = blockIdx.x;
  const float* p = h + (size_t)b * NN * DD + t;
  float acc = 0.f;
  for (int n = 0; n < NN; ++n) acc += p[(size_t)n * DD];
  hm[b * DD + t] = acc * (1.f / NN);
}

// ---------------------------------------------------------------------------
// Per-batch small heads: qv = h_mean@sha_Wq; alloc = softmax(relu(h_mean@W1+b1)@W2+b2)
// ---------------------------------------------------------------------------
__global__ __launch_bounds__(256) void final_small_kernel(
    const float* __restrict__ hm, const float* __restrict__ shaWq,
    const float* __restrict__ W1, const float* __restrict__ b1,
    const float* __restrict__ W2, const float* __restrict__ b2,
    float* __restrict__ qv, float* __restrict__ allocp)
{
  __shared__ float hs[256];
  __shared__ float mids[256];
  __shared__ float red[256];
  const int t = threadIdx.x, b = blockIdx.x;
  hs[t] = hm[b * 256 + t];
  __syncthreads();
  float a = 0.f, m2 = b1[t];
  for (int kk = 0; kk < 256; ++kk) {
    const float hv = hs[kk];
    a  = fmaf(hv, shaWq[kk * 256 + t], a);
    m2 = fmaf(hv, W1[kk * 256 + t], m2);
  }
  qv[b * 256 + t] = a;
  mids[t] = fmaxf(m2, 0.f);
  __syncthreads();
  float lg[4];
#pragma unroll
  for (int j = 0; j < 4; ++j) {
    const int n = t + j * 256;
    float acc2 = b2[n];
    for (int kk = 0; kk < 256; ++kk) acc2 = fmaf(mids[kk], W2[kk * 1024 + n], acc2);
    lg[j] = acc2;
  }
  float m = fmaxf(fmaxf(lg[0], lg[1]), fmaxf(lg[2], lg[3]));
  red[t] = m; __syncthreads();
  for (int s2 = 128; s2; s2 >>= 1) { if (t < s2) red[t] = fmaxf(red[t], red[t + s2]); __syncthreads(); }
  m = red[0]; __syncthreads();
  float e[4]; float ls = 0.f;
#pragma unroll
  for (int j = 0; j < 4; ++j) { e[j] = expf(lg[j] - m); ls += e[j]; }
  red[t] = ls; __syncthreads();
  for (int s2 = 128; s2; s2 >>= 1) { if (t < s2) red[t] += red[t + s2]; __syncthreads(); }
  const float invs = 1.f / red[0];
#pragma unroll
  for (int j = 0; j < 4; ++j) allocp[(size_t)b * 1024 + t + j * 256] = e[j] * invs;
}

// ---------------------------------------------------------------------------
// scores[b,n] = dot(qv[b], kv[b,n])/16; weights = softmax((scores+g)/0.5)
// One block per batch; one wave per kv row (coalesced float4 row reads).
// ---------------------------------------------------------------------------
__global__ __launch_bounds__(256) void scores_kernel(
    const float* __restrict__ qv, const float* __restrict__ kv,
    const float* __restrict__ gum, float* __restrict__ outW,
    float* __restrict__ wcopy)
{
  __shared__ __align__(16) float qs[256];
  __shared__ float sc[1024];
  __shared__ float red[256];
  const int t = threadIdx.x, b = blockIdx.x;
  const int w = t >> 6, lane = t & 63;
  qs[t] = qv[b * 256 + t];
  __syncthreads();
  const float4 myq = *(const float4*)&qs[lane * 4];
  for (int n = w; n < 1024; n += 4) {
    const float4 k4 = *(const float4*)(kv + ((size_t)b * 1024 + n) * 256 + lane * 4);
    float d = myq.x * k4.x + myq.y * k4.y + myq.z * k4.z + myq.w * k4.w;
#pragma unroll
    for (int off = 32; off; off >>= 1) d += __shfl_xor(d, off);
    if (lane == 0) sc[n] = d * (1.f / 16.f);
  }
  __syncthreads();
  float z[4];
#pragma unroll
  for (int j = 0; j < 4; ++j) {
    const int n = t + j * 256;
    z[j] = (sc[n] + gum[(size_t)b * 1024 + n]) * 2.0f;  // /TAU, TAU=0.5
  }
  float m = fmaxf(fmaxf(z[0], z[1]), fmaxf(z[2], z[3]));
  red[t] = m; __syncthreads();
  for (int s2 = 128; s2; s2 >>= 1) { if (t < s2) red[t] = fmaxf(red[t], red[t + s2]); __syncthreads(); }
  m = red[0]; __syncthreads();
  float e[4]; float ls = 0.f;
#pragma unroll
  for (int j = 0; j < 4; ++j) { e[j] = expf(z[j] - m); ls += e[j]; }
  red[t] = ls; __syncthreads();
  for (int s2 = 128; s2; s2 >>= 1) { if (t < s2) red[t] += red[t + s2]; __syncthreads(); }
  const float invs = 1.f / red[0];
#pragma unroll
  for (int j = 0; j < 4; ++j) {
    const int n = t + j * 256;
    const float wv = e[j] * invs;
    outW[(size_t)b * 1024 + n] = wv;
    wcopy[(size_t)b * 1024 + n] = wv;
  }
}

// ---------------------------------------------------------------------------
// Top-64 (descending, ties -> lower index, matching jax.lax.top_k) + sel gather.
// ---------------------------------------------------------------------------
__global__ __launch_bounds__(256) void topk_kernel(
    const float* __restrict__ wcopy, const float* __restrict__ allocp,
    float* __restrict__ outI, float* __restrict__ outS)
{
  __shared__ float wv[1024];
  __shared__ float rv[4];
  __shared__ int   ri[4];
  __shared__ int   sel[64];
  const int t = threadIdx.x, b = blockIdx.x;
  const int w = t >> 6, lane = t & 63;
#pragma unroll
  for (int j = 0; j < 4; ++j) wv[t * 4 + j] = wcopy[(size_t)b * 1024 + t * 4 + j];
  __syncthreads();
  for (int it = 0; it < 64; ++it) {
    float bv = -1.f; int bi = 1 << 20;
#pragma unroll
    for (int j = 0; j < 4; ++j) {
      const int n = t * 4 + j;
      const float v2 = wv[n];
      if (v2 > bv || (v2 == bv && n < bi)) { bv = v2; bi = n; }
    }
#pragma unroll
    for (int off = 32; off; off >>= 1) {
      const float ov = __shfl_xor(bv, off);
      const int   oi = __shfl_xor(bi, off);
      if (ov > bv || (ov == bv && oi < bi)) { bv = ov; bi = oi; }
    }
    if (lane == 0) { rv[w] = bv; ri[w] = bi; }
    __syncthreads();
    if (t == 0) {
      float B2 = rv[0]; int I2 = ri[0];
      for (int u = 1; u < 4; ++u)
        if (rv[u] > B2 || (rv[u] == B2 && ri[u] < I2)) { B2 = rv[u]; I2 = ri[u]; }
      sel[it] = I2;
      wv[I2] = -1.f;   // weights are >= 0, so -1 never re-selected
    }
    __syncthreads();
  }
  if (t < 64) {
    const int idx = sel[t];
    const float sv = allocp[(size_t)b * 1024 + idx];
    float ssum = sv;
#pragma unroll
    for (int off = 32; off; off >>= 1) ssum += __shfl_xor(ssum, off);
    outI[b * 64 + t] = (float)idx;
    outS[b * 64 + t] = sv / (ssum + 1e-12f);
  }
}

// ---------------------------------------------------------------------------
// Host launcher.
// Workspace layout (floats), U = 64*1024*256 = 16,777,216:
//   h     : [0,   U)     persistent activations
//   obuf  : [U,  2U)     attention out -> FFN mid quarters -> final kv
//   carea : [2U, 3.5U)   per-half q/k/v chunks -> FFN fbuf -> final smalls
// Peak footprint: 3.5*U*4 B = 234,881,024 bytes. NOTHING is touched past that.
// ---------------------------------------------------------------------------
extern "C" void kernel_launch(void* const* d_in, const int* in_sizes, int n_in,
                              void* d_out, int out_size, void* d_ws, size_t ws_size,
                              hipStream_t stream)
{
  (void)in_sizes; (void)n_in; (void)out_size; (void)ws_size;
  const float* x      = (const float*)d_in[0];
  const float* gumbel = (const float*)d_in[1];
  const float* emb_W  = (const float*)d_in[2];
  const float* emb_b  = (const float*)d_in[3];
  const float* Wq     = (const float*)d_in[4];
  const float* Wk     = (const float*)d_in[5];
  const float* Wv     = (const float*)d_in[6];
  const float* Wo     = (const float*)d_in[7];
  const float* ln1_g  = (const float*)d_in[8];
  const float* ln1_b  = (const float*)d_in[9];
  const float* ln2_g  = (const float*)d_in[10];
  const float* ln2_b  = (const float*)d_in[11];
  const float* ffn_W1 = (const float*)d_in[12];
  const float* ffn_b1 = (const float*)d_in[13];
  const float* ffn_W2 = (const float*)d_in[14];
  const float* ffn_b2 = (const float*)d_in[15];
  const float* sha_Wq = (const float*)d_in[16];
  const float* sha_Wk = (const float*)d_in[17];
  const float* aW1    = (const float*)d_in[18];
  const float* ab1    = (const float*)d_in[19];
  const float* aW2    = (const float*)d_in[20];
  const float* ab2    = (const float*)d_in[21];

  float* ws = (float*)d_ws;
  const size_t U = (size_t)BB * NN * DD;     // 16,777,216 floats
  float* h     = ws;
  float* obuf  = ws + U;                     // o / FFN-mid quarter / final kv
  float* carea = ws + 2 * U;                 // chunk q/k/v; later fbuf; later smalls
  const size_t HC = U / 2;                   // per-half chunk: 32 batches
  float* qc = carea;
  float* kc = carea + HC;
  float* vc = carea + 2 * HC;
  float* fbuf = carea;                       // [M, 256] accumulator for FFN
  float* hmean  = carea;                     // after loop, carea is free
  float* qvb    = carea + BB * DD;
  float* allocp = carea + 2 * BB * DD;
  float* wcopy  = allocp + (size_t)BB * NN;

  float* outW = (float*)d_out;               // weights [64,1024]
  float* outI = outW + (size_t)BB * NN;      // topk_idx as float [64,64]
  float* outS = outI + BB * KSEL;            // sel [64,64]

  const dim3 blk(256);
  const int M = BB * NN;

  auto GEMM = [&](const float* A, int lda, const float* Bp, int ldb,
                  float* C, int ldc, const float* bias, const float* res,
                  int ldres, int Mm, int Nn, int Kk, int relu, int accum) {
    gemm_kernel<<<dim3(Nn / 64, Mm / 64), blk, 0, stream>>>(
        A, lda, Bp, ldb, C, ldc, bias, res, ldres, Kk, relu, accum);
  };

  embed_kernel<<<dim3(M / 4), blk, 0, stream>>>(x, emb_W, emb_b, h);

  for (int i = 0; i < LL; ++i) {
    const float* wq  = Wq + (size_t)i * DD * DD;
    const float* wk  = Wk + (size_t)i * DD * DD;
    const float* wvp = Wv + (size_t)i * DD * DD;
    const float* wo  = Wo + (size_t)i * DD * DD;
    const float* w1  = ffn_W1 + (size_t)i * DD * DFF2;
    const float* b1  = ffn_b1 + (size_t)i * DFF2;
    const float* w2  = ffn_W2 + (size_t)i * DFF2 * DD;
    const float* b2  = ffn_b2 + (size_t)i * DD;

    // --- attention in two batch halves (q/k/v chunks fit the chunk area) ---
    for (int half = 0; half < 2; ++half) {
      const size_t roff = (size_t)half * (M / 2) * DD;   // = half * HC
      const int Mc = M / 2;
      GEMM(h + roff, DD, wq,  DD, qc, DD, nullptr, nullptr, 0, Mc, DD, DD, 0, 0);
      GEMM(h + roff, DD, wk,  DD, kc, DD, nullptr, nullptr, 0, Mc, DD, DD, 0, 0);
      GEMM(h + roff, DD, wvp, DD, vc, DD, nullptr, nullptr, 0, Mc, DD, DD, 0, 0);
      attn_kernel<<<dim3(NN / 8, HH, BB / 2), blk, 0, stream>>>(qc, kc, vc, obuf + roff);
    }
    GEMM(obuf, DD, wo, DD, h, DD, nullptr, h, DD, M, DD, DD, 0, 0);     // h = h + o@Wo
    ln_kernel<<<dim3(M / 4), blk, 0, stream>>>(h, h, ln1_g + i * DD, ln1_b + i * DD);

    // --- FFN in four 256-column slices: fbuf = h + b2 + sum_c relu(h@W1_c+b1_c)@W2_c ---
    for (int c = 0; c < 4; ++c) {
      GEMM(h, DD, w1 + c * 256, DFF2, obuf, 256, b1 + c * 256, nullptr, 0,
           M, 256, DD, 1, 0);                                            // mid_c (relu)
      GEMM(obuf, 256, w2 + (size_t)c * 256 * DD, DD, fbuf, DD,
           (c == 0) ? b2 : nullptr, (c == 0) ? h : nullptr, DD,
           M, DD, 256, 0, (c == 0) ? 0 : 1);                             // fbuf (+)= mid_c@W2_c
    }
    ln_kernel<<<dim3(M / 4), blk, 0, stream>>>(fbuf, h, ln2_g + i * DD, ln2_b + i * DD);
  }

  rowmean_kernel<<<dim3(BB), blk, 0, stream>>>(h, hmean);
  final_small_kernel<<<dim3(BB), blk, 0, stream>>>(hmean, sha_Wq, aW1, ab1, aW2, ab2, qvb, allocp);
  GEMM(h, DD, sha_Wk, DD, obuf, DD, nullptr, nullptr, 0, M, DD, DD, 0, 0);  // kv into obuf
  scores_kernel<<<dim3(BB), blk, 0, stream>>>(qvb, obuf, gumbel, outW, wcopy);
  topk_kernel<<<dim3(BB), blk, 0, stream>>>(wcopy, allocp, outI, outS);
}

// Round 3
// 10847.668 us; speedup vs baseline: 1.4751x; 1.4751x over previous
//
#include <hip/hip_runtime.h>
#include <math.h>

// Problem constants
#define BB   64
#define NN   1024
#define DIN  16
#define DD   256
#define HH   4
#define LL   3
#define DHH  64
#define DFF2 1024
#define KSEL 64

// ---------------------------------------------------------------------------
// Embedding: h[row, :] = x[row, :16] @ emb_W + emb_b.  4 rows per block.
// ---------------------------------------------------------------------------
__global__ __launch_bounds__(256) void embed_kernel(
    const float* __restrict__ x, const float* __restrict__ W,
    const float* __restrict__ bias, float* __restrict__ h)
{
  __shared__ float xs[4][DIN];
  const int t = threadIdx.x, w = t >> 6, lane = t & 63;
  const size_t row = (size_t)blockIdx.x * 4 + w;
  if (lane < DIN) xs[w][lane] = x[row * DIN + lane];
  __syncthreads();
#pragma unroll
  for (int j = 0; j < 4; ++j) {
    const int col = lane + j * 64;
    float acc = bias[col];
#pragma unroll
    for (int kk = 0; kk < DIN; ++kk) acc = fmaf(xs[w][kk], W[kk * DD + col], acc);
    h[row * DD + col] = acc;
  }
}

// ---------------------------------------------------------------------------
// fp32 GEMM: C[M,N] = A[M,K] @ B[K,N] (+bias)(+res)(relu)(accum)
// 128x128 tile, BK=8, 256 threads, 8x8 micro-tile -> 16 FMA per ds_read_b128.
// As[k][m] transposed at staging (scalar writes, 2-way).  Bs column quads
// stored rotate-interleaved: phys = (cq>>1)|((cq&1)<<4) so the stride-8-float
// reads hit the 2-way bank floor instead of 4-way.
// ---------------------------------------------------------------------------
__global__ __launch_bounds__(256) void gemm128_kernel(
    const float* __restrict__ A, int lda,
    const float* __restrict__ Bm, int ldb,
    float* C, int ldc,
    const float* __restrict__ bias,
    const float* res, int ldres,
    int Kk, int relu, int accum)
{
  __shared__ __align__(16) float As[8][132];
  __shared__ __align__(16) float Bs[8][132];
  const int t = threadIdx.x;
  const int tx = t & 15, ty = t >> 4;
  const size_t row0 = (size_t)blockIdx.y * 128;
  const size_t col0 = (size_t)blockIdx.x * 128;
  // A loader: row = t>>1 (128 rows), k-quad = t&1 (2 quads of BK=8)
  const int arow = t >> 1, aq = (t & 1) * 4;
  // B loader: k-row = t>>5 (8 rows), col-quad = t&31 (32 quads of 128 cols)
  const int brow = t >> 5, bcq = t & 31;
  const int bphys = ((bcq >> 1) | ((bcq & 1) << 4)) * 4;
  float acc[8][8] = {};
  const float* Aptr = A + (row0 + arow) * lda + aq;
  const float* Bptr = Bm + (size_t)brow * ldb + col0 + bcq * 4;

  for (int k0 = 0; k0 < Kk; k0 += 8) {
    const float4 av = *(const float4*)(Aptr + k0);
    const float4 bv = *(const float4*)(Bptr + (size_t)k0 * ldb);
    As[aq + 0][arow] = av.x; As[aq + 1][arow] = av.y;
    As[aq + 2][arow] = av.z; As[aq + 3][arow] = av.w;
    *(float4*)&Bs[brow][bphys] = bv;
    __syncthreads();
#pragma unroll
    for (int kk = 0; kk < 8; ++kk) {
      const float4 a0 = *(const float4*)&As[kk][ty * 8];
      const float4 a1 = *(const float4*)&As[kk][ty * 8 + 4];
      const float4 b0 = *(const float4*)&Bs[kk][tx * 4];       // cols 8tx+0..3
      const float4 b1 = *(const float4*)&Bs[kk][tx * 4 + 64];  // cols 8tx+4..7
      const float aa[8] = {a0.x, a0.y, a0.z, a0.w, a1.x, a1.y, a1.z, a1.w};
      const float bb2[8] = {b0.x, b0.y, b0.z, b0.w, b1.x, b1.y, b1.z, b1.w};
#pragma unroll
      for (int i = 0; i < 8; ++i)
#pragma unroll
        for (int j = 0; j < 8; ++j)
          acc[i][j] = fmaf(aa[i], bb2[j], acc[i][j]);
    }
    __syncthreads();
  }
#pragma unroll
  for (int i = 0; i < 8; ++i) {
    const size_t r = row0 + ty * 8 + i;
    float* cp = C + r * (size_t)ldc + col0 + tx * 8;
    const float* rp = res ? res + r * (size_t)ldres + col0 + tx * 8 : nullptr;
#pragma unroll
    for (int j = 0; j < 8; ++j) {
      const size_t c = col0 + tx * 8 + j;
      float v = acc[i][j];
      if (bias) v += bias[c];
      if (rp)   v += rp[j];
      if (relu) v = fmaxf(v, 0.f);
      if (accum) v += cp[j];
      cp[j] = v;
    }
  }
}

// ---------------------------------------------------------------------------
// Flash attention, fp32.  One block = one (b, head, 64-row q-tile).
// Per k-tile of 64: S = Q K^T (4x4 micro), online softmax in registers,
// P^T -> LDS, O += P V (4x4 micro).  All tiles [64][68] with XOR quad
// swizzle phys_cq = cq ^ ((row>>2)&15): every hot b128 access <=2-way.
// K and V time-share one LDS buffer; next-tile K and this-tile V are
// prefetched into registers under compute.
// ---------------------------------------------------------------------------
#define TOFF(r, cq) ((r) * 68 + 4 * ((cq) ^ (((r) >> 2) & 15)))

__global__ __launch_bounds__(256) void attn_kernel(
    const float* __restrict__ qb, const float* __restrict__ kb,
    const float* __restrict__ vb, float* __restrict__ ob)
{
  __shared__ __align__(16) float Qn[64 * 68];
  __shared__ __align__(16) float KV[64 * 68];
  __shared__ __align__(16) float Pt[64 * 68];
  const int t = threadIdx.x;
  const int tx = t & 15, ty = t >> 4;
  const int qt = blockIdx.x, hh = blockIdx.y, b = blockIdx.z;
  const size_t base = ((size_t)b * NN) * DD + (size_t)hh * DHH;

  // staging geometry: thread loads rows (t>>4)+16u, col-quad (t&15)
  const int srow = t >> 4, scq = t & 15;

  // ---- stage Q tile (rows qt*64 ..) and K tile 0 ----
  {
    const float* qp = qb + base + (size_t)(qt * 64) * DD + scq * 4;
    const float* kp = kb + base + scq * 4;
#pragma unroll
    for (int u = 0; u < 4; ++u) {
      const int r = srow + 16 * u;
      *(float4*)&Qn[TOFF(r, scq)] = *(const float4*)(qp + (size_t)r * DD);
      *(float4*)&KV[TOFF(r, scq)] = *(const float4*)(kp + (size_t)r * DD);
    }
  }

  float S[4][4], O[4][4] = {}, mrun[4], lrun[4] = {};
#pragma unroll
  for (int i = 0; i < 4; ++i) mrun[i] = -1e30f;

  for (int kt = 0; kt < 16; ++kt) {
    __syncthreads();  // bar0: KV holds K_kt, Pt free

    // prefetch V_kt into regs (hidden under QK^T)
    float4 vreg[4];
    {
      const float* vp = vb + base + (size_t)(kt * 64) * DD + scq * 4;
#pragma unroll
      for (int u = 0; u < 4; ++u)
        vreg[u] = *(const float4*)(vp + (size_t)(srow + 16 * u) * DD);
    }

    // ---- S = Q K^T over d=64 ----
#pragma unroll
    for (int i = 0; i < 4; ++i)
#pragma unroll
      for (int j = 0; j < 4; ++j) S[i][j] = 0.f;
#pragma unroll
    for (int dq = 0; dq < 16; ++dq) {
      float4 q4[4], k4[4];
#pragma unroll
      for (int ii = 0; ii < 4; ++ii) q4[ii] = *(const float4*)&Qn[TOFF(4 * ty + ii, dq)];
#pragma unroll
      for (int jj = 0; jj < 4; ++jj) k4[jj] = *(const float4*)&KV[TOFF(4 * tx + jj, dq)];
#pragma unroll
      for (int ii = 0; ii < 4; ++ii)
#pragma unroll
        for (int jj = 0; jj < 4; ++jj)
          S[ii][jj] += q4[ii].x * k4[jj].x + q4[ii].y * k4[jj].y +
                       q4[ii].z * k4[jj].z + q4[ii].w * k4[jj].w;
    }

    // ---- online softmax (rows 4ty+ii; 16-lane tx-groups share a row) ----
    float alpha[4];
#pragma unroll
    for (int ii = 0; ii < 4; ++ii) {
      float mt = -1e30f;
#pragma unroll
      for (int jj = 0; jj < 4; ++jj) { S[ii][jj] *= 0.125f; mt = fmaxf(mt, S[ii][jj]); }
#pragma unroll
      for (int off = 1; off < 16; off <<= 1) mt = fmaxf(mt, __shfl_xor(mt, off));
      const float mnew = fmaxf(mrun[ii], mt);
      alpha[ii] = __expf(mrun[ii] - mnew);
      mrun[ii] = mnew;
      float rs = 0.f;
#pragma unroll
      for (int jj = 0; jj < 4; ++jj) { S[ii][jj] = __expf(S[ii][jj] - mnew); rs += S[ii][jj]; }
#pragma unroll
      for (int off = 1; off < 16; off <<= 1) rs += __shfl_xor(rs, off);
      lrun[ii] = lrun[ii] * alpha[ii] + rs;
    }
    // write P^T: row = k-col (4tx+jj), col-quad = ty
#pragma unroll
    for (int jj = 0; jj < 4; ++jj) {
      float4 pv = {S[0][jj], S[1][jj], S[2][jj], S[3][jj]};
      *(float4*)&Pt[TOFF(4 * tx + jj, ty)] = pv;
    }

    __syncthreads();  // bar1: K reads done, Pt visible

    // V regs -> KV
#pragma unroll
    for (int u = 0; u < 4; ++u)
      *(float4*)&KV[TOFF(srow + 16 * u, scq)] = vreg[u];

    // prefetch K_{kt+1} into regs (hidden under PV)
    float4 kreg[4];
    {
      const int ktn = (kt + 1) & 15;
      const float* kp = kb + base + (size_t)(ktn * 64) * DD + scq * 4;
#pragma unroll
      for (int u = 0; u < 4; ++u)
        kreg[u] = *(const float4*)(kp + (size_t)(srow + 16 * u) * DD);
    }

    __syncthreads();  // bar2: V ready

    // ---- O = O*alpha + P V ----
#pragma unroll
    for (int ii = 0; ii < 4; ++ii)
#pragma unroll
      for (int jj = 0; jj < 4; ++jj) O[ii][jj] *= alpha[ii];
#pragma unroll
    for (int c = 0; c < 64; ++c) {
      const float4 p4 = *(const float4*)&Pt[TOFF(c, ty)];
      const float4 v4 = *(const float4*)&KV[TOFF(c, tx)];
      const float pp[4] = {p4.x, p4.y, p4.z, p4.w};
      const float vv[4] = {v4.x, v4.y, v4.z, v4.w};
#pragma unroll
      for (int ii = 0; ii < 4; ++ii)
#pragma unroll
        for (int jj = 0; jj < 4; ++jj)
          O[ii][jj] = fmaf(pp[ii], vv[jj], O[ii][jj]);
    }

    __syncthreads();  // bar3: V/Pt reads done

    // K regs -> KV (for next iteration's bar0)
#pragma unroll
    for (int u = 0; u < 4; ++u)
      *(float4*)&KV[TOFF(srow + 16 * u, scq)] = kreg[u];
  }

  // ---- write O / l ----
#pragma unroll
  for (int ii = 0; ii < 4; ++ii) {
    const float inv = 1.f / lrun[ii];
    float4 o4 = {O[ii][0] * inv, O[ii][1] * inv, O[ii][2] * inv, O[ii][3] * inv};
    *(float4*)(ob + base + (size_t)(qt * 64 + 4 * ty + ii) * DD + 4 * tx) = o4;
  }
}

// ---------------------------------------------------------------------------
// LayerNorm over D=256, 4 rows/block (one wave per row, shfl reduce).
// ---------------------------------------------------------------------------
__global__ __launch_bounds__(256) void ln_kernel(
    const float* in, float* out,
    const float* __restrict__ g, const float* __restrict__ bb)
{
  const int t = threadIdx.x, w = t >> 6, lane = t & 63;
  const size_t row = (size_t)blockIdx.x * 4 + w;
  const float4 val = *(const float4*)(in + row * DD + lane * 4);
  float s = val.x + val.y + val.z + val.w;
#pragma unroll
  for (int off = 32; off; off >>= 1) s += __shfl_xor(s, off);
  const float mean = s * (1.f / 256.f);
  const float dx = val.x - mean, dy = val.y - mean, dz = val.z - mean, dw = val.w - mean;
  float ss = dx * dx + dy * dy + dz * dz + dw * dw;
#pragma unroll
  for (int off = 32; off; off >>= 1) ss += __shfl_xor(ss, off);
  const float inv = rsqrtf(ss * (1.f / 256.f) + 1e-5f);
  const float4 g4 = *(const float4*)(g + lane * 4);
  const float4 b4 = *(const float4*)(bb + lane * 4);
  float4 o4;
  o4.x = dx * inv * g4.x + b4.x;
  o4.y = dy * inv * g4.y + b4.y;
  o4.z = dz * inv * g4.z + b4.z;
  o4.w = dw * inv * g4.w + b4.w;
  *(float4*)(out + row * DD + lane * 4) = o4;
}

// ---------------------------------------------------------------------------
// h_mean[b, :] = mean over N of h[b, :, :]
// ---------------------------------------------------------------------------
__global__ __launch_bounds__(256) void rowmean_kernel(
    const float* __restrict__ h, float* __restrict__ hm)
{
  const int t = threadIdx.x, b = blockIdx.x;
  const float* p = h + (size_t)b * NN * DD + t;
  float acc = 0.f;
  for (int n = 0; n < NN; ++n) acc += p[(size_t)n * DD];
  hm[b * DD + t] = acc * (1.f / NN);
}

// ---------------------------------------------------------------------------
// Per-batch small heads: qv = h_mean@sha_Wq; alloc = softmax(relu(h_mean@W1+b1)@W2+b2)
// ---------------------------------------------------------------------------
__global__ __launch_bounds__(256) void final_small_kernel(
    const float* __restrict__ hm, const float* __restrict__ shaWq,
    const float* __restrict__ W1, const float* __restrict__ b1,
    const float* __restrict__ W2, const float* __restrict__ b2,
    float* __restrict__ qv, float* __restrict__ allocp)
{
  __shared__ float hs[256];
  __shared__ float mids[256];
  __shared__ float red[256];
  const int t = threadIdx.x, b = blockIdx.x;
  hs[t] = hm[b * 256 + t];
  __syncthreads();
  float a = 0.f, m2 = b1[t];
  for (int kk = 0; kk < 256; ++kk) {
    const float hv = hs[kk];
    a  = fmaf(hv, shaWq[kk * 256 + t], a);
    m2 = fmaf(hv, W1[kk * 256 + t], m2);
  }
  qv[b * 256 + t] = a;
  mids[t] = fmaxf(m2, 0.f);
  __syncthreads();
  float lg[4];
#pragma unroll
  for (int j = 0; j < 4; ++j) {
    const int n = t + j * 256;
    float acc2 = b2[n];
    for (int kk = 0; kk < 256; ++kk) acc2 = fmaf(mids[kk], W2[kk * 1024 + n], acc2);
    lg[j] = acc2;
  }
  float m = fmaxf(fmaxf(lg[0], lg[1]), fmaxf(lg[2], lg[3]));
  red[t] = m; __syncthreads();
  for (int s2 = 128; s2; s2 >>= 1) { if (t < s2) red[t] = fmaxf(red[t], red[t + s2]); __syncthreads(); }
  m = red[0]; __syncthreads();
  float e[4]; float ls = 0.f;
#pragma unroll
  for (int j = 0; j < 4; ++j) { e[j] = expf(lg[j] - m); ls += e[j]; }
  red[t] = ls; __syncthreads();
  for (int s2 = 128; s2; s2 >>= 1) { if (t < s2) red[t] += red[t + s2]; __syncthreads(); }
  const float invs = 1.f / red[0];
#pragma unroll
  for (int j = 0; j < 4; ++j) allocp[(size_t)b * 1024 + t + j * 256] = e[j] * invs;
}

// ---------------------------------------------------------------------------
// scores[b,n] = dot(qv[b], kv[b,n])/16; weights = softmax((scores+g)/0.5)
// ---------------------------------------------------------------------------
__global__ __launch_bounds__(256) void scores_kernel(
    const float* __restrict__ qv, const float* __restrict__ kv,
    const float* __restrict__ gum, float* __restrict__ outW,
    float* __restrict__ wcopy)
{
  __shared__ __align__(16) float qs[256];
  __shared__ float sc[1024];
  __shared__ float red[256];
  const int t = threadIdx.x, b = blockIdx.x;
  const int w = t >> 6, lane = t & 63;
  qs[t] = qv[b * 256 + t];
  __syncthreads();
  const float4 myq = *(const float4*)&qs[lane * 4];
  for (int n = w; n < 1024; n += 4) {
    const float4 k4 = *(const float4*)(kv + ((size_t)b * 1024 + n) * 256 + lane * 4);
    float d = myq.x * k4.x + myq.y * k4.y + myq.z * k4.z + myq.w * k4.w;
#pragma unroll
    for (int off = 32; off; off >>= 1) d += __shfl_xor(d, off);
    if (lane == 0) sc[n] = d * (1.f / 16.f);
  }
  __syncthreads();
  float z[4];
#pragma unroll
  for (int j = 0; j < 4; ++j) {
    const int n = t + j * 256;
    z[j] = (sc[n] + gum[(size_t)b * 1024 + n]) * 2.0f;  // /TAU, TAU=0.5
  }
  float m = fmaxf(fmaxf(z[0], z[1]), fmaxf(z[2], z[3]));
  red[t] = m; __syncthreads();
  for (int s2 = 128; s2; s2 >>= 1) { if (t < s2) red[t] = fmaxf(red[t], red[t + s2]); __syncthreads(); }
  m = red[0]; __syncthreads();
  float e[4]; float ls = 0.f;
#pragma unroll
  for (int j = 0; j < 4; ++j) { e[j] = expf(z[j] - m); ls += e[j]; }
  red[t] = ls; __syncthreads();
  for (int s2 = 128; s2; s2 >>= 1) { if (t < s2) red[t] += red[t + s2]; __syncthreads(); }
  const float invs = 1.f / red[0];
#pragma unroll
  for (int j = 0; j < 4; ++j) {
    const int n = t + j * 256;
    const float wv = e[j] * invs;
    outW[(size_t)b * 1024 + n] = wv;
    wcopy[(size_t)b * 1024 + n] = wv;
  }
}

// ---------------------------------------------------------------------------
// Top-64 (descending, ties -> lower index, matching jax.lax.top_k) + sel gather.
// ---------------------------------------------------------------------------
__global__ __launch_bounds__(256) void topk_kernel(
    const float* __restrict__ wcopy, const float* __restrict__ allocp,
    float* __restrict__ outI, float* __restrict__ outS)
{
  __shared__ float wv[1024];
  __shared__ float rv[4];
  __shared__ int   ri[4];
  __shared__ int   sel[64];
  const int t = threadIdx.x, b = blockIdx.x;
  const int w = t >> 6, lane = t & 63;
#pragma unroll
  for (int j = 0; j < 4; ++j) wv[t * 4 + j] = wcopy[(size_t)b * 1024 + t * 4 + j];
  __syncthreads();
  for (int it = 0; it < 64; ++it) {
    float bv = -1.f; int bi = 1 << 20;
#pragma unroll
    for (int j = 0; j < 4; ++j) {
      const int n = t * 4 + j;
      const float v2 = wv[n];
      if (v2 > bv || (v2 == bv && n < bi)) { bv = v2; bi = n; }
    }
#pragma unroll
    for (int off = 32; off; off >>= 1) {
      const float ov = __shfl_xor(bv, off);
      const int   oi = __shfl_xor(bi, off);
      if (ov > bv || (ov == bv && oi < bi)) { bv = ov; bi = oi; }
    }
    if (lane == 0) { rv[w] = bv; ri[w] = bi; }
    __syncthreads();
    if (t == 0) {
      float B2 = rv[0]; int I2 = ri[0];
      for (int u = 1; u < 4; ++u)
        if (rv[u] > B2 || (rv[u] == B2 && ri[u] < I2)) { B2 = rv[u]; I2 = ri[u]; }
      sel[it] = I2;
      wv[I2] = -1.f;
    }
    __syncthreads();
  }
  if (t < 64) {
    const int idx = sel[t];
    const float sv = allocp[(size_t)b * 1024 + idx];
    float ssum = sv;
#pragma unroll
    for (int off = 32; off; off >>= 1) ssum += __shfl_xor(ssum, off);
    outI[b * 64 + t] = (float)idx;
    outS[b * 64 + t] = sv / (ssum + 1e-12f);
  }
}

// ---------------------------------------------------------------------------
// Host launcher.  Workspace (floats), U = 16,777,216:
//   h [0,U) | obuf [U,2U) | carea [2U,3.5U)  -- peak 3.5U*4 B = 224 MiB.
// ---------------------------------------------------------------------------
extern "C" void kernel_launch(void* const* d_in, const int* in_sizes, int n_in,
                              void* d_out, int out_size, void* d_ws, size_t ws_size,
                              hipStream_t stream)
{
  (void)in_sizes; (void)n_in; (void)out_size; (void)ws_size;
  const float* x      = (const float*)d_in[0];
  const float* gumbel = (const float*)d_in[1];
  const float* emb_W  = (const float*)d_in[2];
  const float* emb_b  = (const float*)d_in[3];
  const float* Wq     = (const float*)d_in[4];
  const float* Wk     = (const float*)d_in[5];
  const float* Wv     = (const float*)d_in[6];
  const float* Wo     = (const float*)d_in[7];
  const float* ln1_g  = (const float*)d_in[8];
  const float* ln1_b  = (const float*)d_in[9];
  const float* ln2_g  = (const float*)d_in[10];
  const float* ln2_b  = (const float*)d_in[11];
  const float* ffn_W1 = (const float*)d_in[12];
  const float* ffn_b1 = (const float*)d_in[13];
  const float* ffn_W2 = (const float*)d_in[14];
  const float* ffn_b2 = (const float*)d_in[15];
  const float* sha_Wq = (const float*)d_in[16];
  const float* sha_Wk = (const float*)d_in[17];
  const float* aW1    = (const float*)d_in[18];
  const float* ab1    = (const float*)d_in[19];
  const float* aW2    = (const float*)d_in[20];
  const float* ab2    = (const float*)d_in[21];

  float* ws = (float*)d_ws;
  const size_t U = (size_t)BB * NN * DD;
  float* h     = ws;
  float* obuf  = ws + U;
  float* carea = ws + 2 * U;
  const size_t HC = U / 2;
  float* qc = carea;
  float* kc = carea + HC;
  float* vc = carea + 2 * HC;
  float* fbuf = carea;
  float* hmean  = carea;
  float* qvb    = carea + BB * DD;
  float* allocp = carea + 2 * BB * DD;
  float* wcopy  = allocp + (size_t)BB * NN;

  float* outW = (float*)d_out;
  float* outI = outW + (size_t)BB * NN;
  float* outS = outI + BB * KSEL;

  const dim3 blk(256);
  const int M = BB * NN;

  auto GEMM = [&](const float* A, int lda, const float* Bp, int ldb,
                  float* C, int ldc, const float* bias, const float* res,
                  int ldres, int Mm, int Nn, int Kk, int relu, int accum) {
    gemm128_kernel<<<dim3(Nn / 128, Mm / 128), blk, 0, stream>>>(
        A, lda, Bp, ldb, C, ldc, bias, res, ldres, Kk, relu, accum);
  };

  embed_kernel<<<dim3(M / 4), blk, 0, stream>>>(x, emb_W, emb_b, h);

  for (int i = 0; i < LL; ++i) {
    const float* wq  = Wq + (size_t)i * DD * DD;
    const float* wk  = Wk + (size_t)i * DD * DD;
    const float* wvp = Wv + (size_t)i * DD * DD;
    const float* wo  = Wo + (size_t)i * DD * DD;
    const float* w1  = ffn_W1 + (size_t)i * DD * DFF2;
    const float* b1  = ffn_b1 + (size_t)i * DFF2;
    const float* w2  = ffn_W2 + (size_t)i * DFF2 * DD;
    const float* b2  = ffn_b2 + (size_t)i * DD;

    for (int half = 0; half < 2; ++half) {
      const size_t roff = (size_t)half * (M / 2) * DD;
      const int Mc = M / 2;
      GEMM(h + roff, DD, wq,  DD, qc, DD, nullptr, nullptr, 0, Mc, DD, DD, 0, 0);
      GEMM(h + roff, DD, wk,  DD, kc, DD, nullptr, nullptr, 0, Mc, DD, DD, 0, 0);
      GEMM(h + roff, DD, wvp, DD, vc, DD, nullptr, nullptr, 0, Mc, DD, DD, 0, 0);
      attn_kernel<<<dim3(NN / 64, HH, BB / 2), blk, 0, stream>>>(qc, kc, vc, obuf + roff);
    }
    GEMM(obuf, DD, wo, DD, h, DD, nullptr, h, DD, M, DD, DD, 0, 0);
    ln_kernel<<<dim3(M / 4), blk, 0, stream>>>(h, h, ln1_g + i * DD, ln1_b + i * DD);

    for (int c = 0; c < 4; ++c) {
      GEMM(h, DD, w1 + c * 256, DFF2, obuf, 256, b1 + c * 256, nullptr, 0,
           M, 256, DD, 1, 0);
      GEMM(obuf, 256, w2 + (size_t)c * 256 * DD, DD, fbuf, DD,
           (c == 0) ? b2 : nullptr, (c == 0) ? h : nullptr, DD,
           M, DD, 256, 0, (c == 0) ? 0 : 1);
    }
    ln_kernel<<<dim3(M / 4), blk, 0, stream>>>(fbuf, h, ln2_g + i * DD, ln2_b + i * DD);
  }

  rowmean_kernel<<<dim3(BB), blk, 0, stream>>>(h, hmean);
  final_small_kernel<<<dim3(BB), blk, 0, stream>>>(hmean, sha_Wq, aW1, ab1, aW2, ab2, qvb, allocp);
  GEMM(h, DD, sha_Wk, DD, obuf, DD, nullptr, nullptr, 0, M, DD, DD, 0, 0);
  scores_kernel<<<dim3(BB), blk, 0, stream>>>(qvb, obuf, gumbel, outW, wcopy);
  topk_kernel<<<dim3(BB), blk, 0, stream>>>(wcopy, allocp, outI, outS);
}